// Round 2
// baseline (2851.380 us; speedup 1.0000x reference)
//
#include <hip/hip_runtime.h>
#include <cstdint>
#include <cstddef>

#define B 64
#define PCH 512
#define O_CAPS 32
#define OD 16
#define IDC 8
#define I_CAPS 4096
#define ICHUNK 16
#define NPBLK 256  // I_CAPS / ICHUNK
#define Z 64
#define HDIM 1024

// workspace layout (in floats)
#define OFF_POSE 0
#define SZ_POSE (B * I_CAPS * IDC)                    // 2,097,152
#define OFF_BLOG (OFF_POSE + SZ_POSE)
#define SZ_BLOG ((size_t)B * I_CAPS * O_CAPS)         // 8,388,608
#define OFF_PART (OFF_BLOG + SZ_BLOG)
#define SZ_PART ((size_t)NPBLK * 2 * 32 * 512)        // 8,388,608
#define OFF_VBUF (OFF_PART + SZ_PART)
#define SZ_V (B * O_CAPS * OD)                        // 32,768
#define OFF_OUTC (OFF_VBUF + SZ_V)
#define OFF_WT (OFF_OUTC + SZ_V)
#define SZ_WT (PCH * 9 * PCH)                         // 2,359,296
#define OFF_BIAS (OFF_WT + SZ_WT)
#define OFF_H OFF_BLOG  // reuse blog region for h (blog dead by then)

// ---------------------------------------------------------------------------
// K0: transpose conv weights to [ci*9+tap][co] (co fast) with BN scale folded;
// also compute folded bias. Coalesced reads; scattered writes (one-time 9.4MB).
// ---------------------------------------------------------------------------
__global__ __launch_bounds__(256) void prep_w(
    const float* __restrict__ cw, const float* __restrict__ gamma,
    const float* __restrict__ beta, const float* __restrict__ mean,
    const float* __restrict__ var, float* __restrict__ wt,
    float* __restrict__ bias) {
  const int co = blockIdx.x;  // 512 blocks
  const float inv = gamma[co] * rsqrtf(var[co] + 1e-5f);
  if (threadIdx.x == 0) bias[co] = beta[co] - mean[co] * inv;
  for (int idx = threadIdx.x; idx < PCH * 9; idx += 256)
    wt[(size_t)idx * PCH + co] = cw[(size_t)co * (PCH * 9) + idx] * inv;
}

// ---------------------------------------------------------------------------
// K1: conv3x3 SAME + folded BN + ReLU + squash(k=8) -> pose[b,i,k]
// block: (b, co-tile of 64). 256 threads = 64 px * 4 co-groups of 16.
// lx padded to 10x10 with zero halo -> unconditional taps.
// lw staged from pre-transposed wt -> conflict-free LDS writes.
// ---------------------------------------------------------------------------
__global__ __launch_bounds__(256) void conv_bn_squash(
    const float* __restrict__ x, const float* __restrict__ wt,
    const float* __restrict__ bias, float* __restrict__ pose) {
  __shared__ float lx[16 * 100];       // 6.25 KB, 10x10 padded per ci
  __shared__ float lw[16 * 9 * 64];    // 36 KB: [ci*9+tap][co]
  __shared__ float lbias[64];
  const int b = blockIdx.x;
  const int co0 = blockIdx.y * 64;
  const int tid = threadIdx.x;
  if (tid < 64) lbias[tid] = bias[co0 + tid];
  // zero the halo (whole buffer once; interiors overwritten each chunk)
  for (int t = tid; t < 1600; t += 256) lx[t] = 0.f;

  const int p = tid & 63, cg = tid >> 6;
  const int h = p >> 3, w = p & 7;
  float acc[16];
#pragma unroll
  for (int c = 0; c < 16; ++c) acc[c] = 0.f;

  for (int ci0 = 0; ci0 < PCH; ci0 += 16) {
    __syncthreads();
    for (int idx = tid; idx < 1024; idx += 256) {
      const int ci = idx >> 6, px = idx & 63;
      lx[ci * 100 + 11 + (px >> 3) * 10 + (px & 7)] =
          x[((size_t)b * PCH + ci0 + ci) * 64 + px];
    }
    for (int idx = tid; idx < 9216; idx += 256) {
      const int r = idx >> 6, c = idx & 63;  // r = ci*9+tap
      lw[idx] = wt[(size_t)(ci0 * 9 + r) * PCH + co0 + c];
    }
    __syncthreads();
    for (int ci = 0; ci < 16; ++ci) {
      const float* lxp = lx + ci * 100 + h * 10 + w;
      float xv[9];
      xv[0] = lxp[0];  xv[1] = lxp[1];  xv[2] = lxp[2];
      xv[3] = lxp[10]; xv[4] = lxp[11]; xv[5] = lxp[12];
      xv[6] = lxp[20]; xv[7] = lxp[21]; xv[8] = lxp[22];
#pragma unroll
      for (int t = 0; t < 9; ++t) {
        const float4* wq = (const float4*)&lw[(ci * 9 + t) * 64 + cg * 16];
#pragma unroll
        for (int q = 0; q < 4; ++q) {
          const float4 wv = wq[q];
          acc[q * 4 + 0] += wv.x * xv[t];
          acc[q * 4 + 1] += wv.y * xv[t];
          acc[q * 4 + 2] += wv.z * xv[t];
          acc[q * 4 + 3] += wv.w * xv[t];
        }
      }
    }
  }
  // epilogue: bias + relu + squash over each group of 8 channels
#pragma unroll
  for (int c = 0; c < 16; ++c) acc[c] = fmaxf(acc[c] + lbias[cg * 16 + c], 0.f);
#pragma unroll
  for (int g = 0; g < 2; ++g) {
    float ms = 0.f;
#pragma unroll
    for (int j = 0; j < 8; ++j) ms += acc[g * 8 + j] * acc[g * 8 + j];
    const float sc = ms / (1.f + ms) / (sqrtf(ms) + 1e-8f);
    const int cap = (co0 >> 3) + cg * 2 + g;
    float* dst = pose + ((size_t)b * I_CAPS + cap * 64 + p) * IDC;
#pragma unroll
    for (int j = 0; j < 8; ++j) dst[j] = acc[g * 8 + j] * sc;
  }
}

// ---------------------------------------------------------------------------
// Routing phase v2: wave wv handles i = i0 + wv*2 + {0,1}, ALL 32 b-rows.
// W-slice read once per block (no 8x wave redundancy). Whole wave shares
// (b,i); lane = o*2+dh. Softmax via shfl. LDS accumulation via atomicAdd
// (cross-wave races on same (bl,d,o) resolved by HW).
// ---------------------------------------------------------------------------
template <int MODE>
__global__ __launch_bounds__(512, 4) void routing_phase(
    const float* __restrict__ pose, const float* __restrict__ capsw,
    const float* __restrict__ vbuf, float* __restrict__ blog,
    float* __restrict__ partials) {
  __shared__ float acc[32 * 512];  // 64 KB
  const int tid = threadIdx.x;
  const int lane = tid & 63;
  const int wv = tid >> 6;
  const int o = lane >> 1, dh = lane & 1;
  const int i0 = blockIdx.x * ICHUNK;
  const int b0 = blockIdx.y * 32;

  for (int t = tid; t < 32 * 512; t += 512) acc[t] = 0.f;
  __syncthreads();

  const float* wbase =
      capsw + (size_t)o * ((size_t)I_CAPS * OD * IDC) + (size_t)dh * 64;

  for (int ii = 0; ii < 2; ++ii) {
    const int i = i0 + wv * 2 + ii;
    float wf[64];  // W[o][i][dh*8 + j][k], 64 contiguous floats
    const float4* wp = (const float4*)(wbase + (size_t)i * (OD * IDC));
#pragma unroll
    for (int q = 0; q < 16; ++q) {
      const float4 v4 = wp[q];
      wf[q * 4 + 0] = v4.x; wf[q * 4 + 1] = v4.y;
      wf[q * 4 + 2] = v4.z; wf[q * 4 + 3] = v4.w;
    }
    for (int bl = 0; bl < 32; ++bl) {
      const int b = b0 + bl;
      const float4* pp = (const float4*)(pose + ((size_t)b * I_CAPS + i) * IDC);
      const float4 p0 = pp[0], p1 = pp[1];
      const float pk[8] = {p0.x, p0.y, p0.z, p0.w, p1.x, p1.y, p1.z, p1.w};
      float X[8];
#pragma unroll
      for (int j = 0; j < 8; ++j) {
        float s = 0.f;
#pragma unroll
        for (int k = 0; k < 8; ++k) s += wf[j * 8 + k] * pk[k];
        X[j] = s;
      }
      float c;
      if (MODE == 0) {
        c = 1.0f / 32.0f;
      } else {
        const float* vrow = vbuf + ((size_t)(b * O_CAPS + o) * OD) + dh * 8;
        float lg = 0.f;
#pragma unroll
        for (int j = 0; j < 8; ++j) lg += vrow[j] * X[j];
        lg += __shfl_xor(lg, 1, 64);  // full v.X over 16 d on both halves
        const size_t bidx = ((size_t)b * I_CAPS + i) * O_CAPS + o;
        if (MODE == 2) lg += blog[bidx];
        if (MODE == 1 && dh == 0) blog[bidx] = lg;
        float mx = lg;
#pragma unroll
        for (int s = 2; s < 64; s <<= 1) mx = fmaxf(mx, __shfl_xor(mx, s, 64));
        const float e = __expf(lg - mx);
        float sm = e;
#pragma unroll
        for (int s = 2; s < 64; s <<= 1) sm += __shfl_xor(sm, s, 64);
        c = e / sm;
      }
      // acc layout [bl][d][o]: 2-way-only bank aliasing; atomic vs other waves
      float* ab = acc + (bl * 512 + dh * 256 + o);
#pragma unroll
      for (int j = 0; j < 8; ++j) atomicAdd(ab + j * 32, c * X[j]);
    }
  }
  __syncthreads();
  float* dst = partials + (size_t)(blockIdx.x * 2 + blockIdx.y) * (32 * 512);
  for (int t = tid; t < 32 * 512; t += 512) dst[t] = acc[t];
}

// ---------------------------------------------------------------------------
// Reduce partials over the 256 i-chunks, then squash over d (16) -> dst[b,o,d]
// ---------------------------------------------------------------------------
__global__ __launch_bounds__(256) void reduce_squash(
    const float* __restrict__ partials, float* __restrict__ dst) {
  const int t = blockIdx.x * 256 + threadIdx.x;  // 0..32767 -> (b,o,d)
  const int b = t >> 9;
  const int r = t & 511;
  const int o = r >> 4, d = r & 15;
  const int bh = b >> 5, bl = b & 31;
  const size_t elem = (size_t)bl * 512 + (size_t)d * 32 + o;
  float s = 0.f;
  for (int blk = 0; blk < NPBLK; ++blk)
    s += partials[(size_t)(blk * 2 + bh) * (32 * 512) + elem];
  float sq = s * s;
  sq += __shfl_xor(sq, 1, 64);
  sq += __shfl_xor(sq, 2, 64);
  sq += __shfl_xor(sq, 4, 64);
  sq += __shfl_xor(sq, 8, 64);
  const float sc = sq / (1.f + sq) / (sqrtf(sq) + 1e-8f);
  dst[t] = s * sc;
}

// ---------------------------------------------------------------------------
// VAE head
// ---------------------------------------------------------------------------
__global__ __launch_bounds__(256) void fc1_relu(
    const float* __restrict__ outc, const float* __restrict__ w1,
    const float* __restrict__ b1, float* __restrict__ h) {
  const int gid = blockIdx.x * 256 + threadIdx.x;  // < 2048*1024
  const int n = gid >> 10, j = gid & 1023;
  float s = b1[j];
#pragma unroll
  for (int k = 0; k < 16; ++k) s += outc[n * 16 + k] * w1[k * 1024 + j];
  h[gid] = fmaxf(s, 0.f);
}

__global__ __launch_bounds__(256) void fc2_mu(
    const float* __restrict__ h, const float* __restrict__ w2,
    const float* __restrict__ b2, float* __restrict__ dout) {
  __shared__ float lh[4 * 1024];
  const int tid = threadIdx.x;
  const int nl = tid >> 6, m = tid & 63;
  const int n0 = blockIdx.x * 4;
  for (int idx = tid; idx < 4096; idx += 256)
    lh[idx] = h[(size_t)n0 * 1024 + idx];
  __syncthreads();
  float s = b2[m];
  const float* hr = lh + nl * 1024;
#pragma unroll 8
  for (int j = 0; j < 1024; ++j) s += hr[j] * w2[j * 64 + m];
  const int n = n0 + nl;
  dout[n * 64 + m] = s;            // z
  dout[131072 + n * 64 + m] = s;   // z_mu
}

__global__ __launch_bounds__(256) void fc_var(
    const float* __restrict__ outc, const float* __restrict__ wv,
    const float* __restrict__ bv, float* __restrict__ dout) {
  const int gid = blockIdx.x * 256 + threadIdx.x;  // < 131072
  const int n = gid >> 6, m = gid & 63;
  float s = bv[m];
#pragma unroll
  for (int k = 0; k < 16; ++k) s += outc[n * 16 + k] * wv[k * 64 + m];
  const float sp = (s > 0.f) ? (s + log1pf(__expf(-s))) : log1pf(__expf(s));
  dout[262144 + gid] = sp + 1e-8f;
}

// ---------------------------------------------------------------------------
extern "C" void kernel_launch(void* const* d_in, const int* in_sizes, int n_in,
                              void* d_out, int out_size, void* d_ws,
                              size_t ws_size, hipStream_t stream) {
  const float* x = (const float*)d_in[0];
  const float* conv_w = (const float*)d_in[1];
  const float* bn_gamma = (const float*)d_in[2];
  const float* bn_beta = (const float*)d_in[3];
  const float* bn_mean = (const float*)d_in[4];
  const float* bn_var = (const float*)d_in[5];
  const float* caps_w = (const float*)d_in[6];
  const float* fcm_w1 = (const float*)d_in[7];
  const float* fcm_b1 = (const float*)d_in[8];
  const float* fcm_w2 = (const float*)d_in[9];
  const float* fcm_b2 = (const float*)d_in[10];
  const float* fcv_w = (const float*)d_in[11];
  const float* fcv_b = (const float*)d_in[12];
  float* out = (float*)d_out;
  float* ws = (float*)d_ws;

  float* pose = ws + OFF_POSE;
  float* blog = ws + OFF_BLOG;
  float* part = ws + OFF_PART;
  float* vbuf = ws + OFF_VBUF;
  float* outc = ws + OFF_OUTC;
  float* wt = ws + OFF_WT;
  float* bias = ws + OFF_BIAS;
  float* h = ws + OFF_H;

  prep_w<<<512, 256, 0, stream>>>(conv_w, bn_gamma, bn_beta, bn_mean, bn_var,
                                  wt, bias);
  conv_bn_squash<<<dim3(64, 8), 256, 0, stream>>>(x, wt, bias, pose);

  routing_phase<0><<<dim3(NPBLK, 2), 512, 0, stream>>>(
      pose, caps_w, nullptr, nullptr, part);
  reduce_squash<<<128, 256, 0, stream>>>(part, vbuf);

  routing_phase<1><<<dim3(NPBLK, 2), 512, 0, stream>>>(
      pose, caps_w, vbuf, blog, part);
  reduce_squash<<<128, 256, 0, stream>>>(part, vbuf);

  routing_phase<2><<<dim3(NPBLK, 2), 512, 0, stream>>>(
      pose, caps_w, vbuf, blog, part);
  reduce_squash<<<128, 256, 0, stream>>>(part, outc);

  fc1_relu<<<8192, 256, 0, stream>>>(outc, fcm_w1, fcm_b1, h);
  fc2_mu<<<512, 256, 0, stream>>>(h, fcm_w2, fcm_b2, out);
  fc_var<<<512, 256, 0, stream>>>(outc, fcv_w, fcv_b, out);
}

// Round 3
// 971.714 us; speedup vs baseline: 2.9344x; 2.9344x over previous
//
#include <hip/hip_runtime.h>
#include <cstdint>
#include <cstddef>

#define B 64
#define PCH 512
#define O_CAPS 32
#define OD 16
#define IDC 8
#define I_CAPS 4096
#define ICHUNK 16
#define NPBLK 256  // I_CAPS / ICHUNK
#define Z 64
#define HDIM 1024

// workspace layout (in floats)
#define OFF_POSE 0
#define SZ_POSE (B * I_CAPS * IDC)                    // 2,097,152
#define OFF_BLOG (OFF_POSE + SZ_POSE)
#define SZ_BLOG ((size_t)B * I_CAPS * O_CAPS)         // 8,388,608
#define OFF_PART (OFF_BLOG + SZ_BLOG)
#define SZ_PART ((size_t)NPBLK * 2 * 32 * 512)        // 8,388,608
#define OFF_VBUF (OFF_PART + SZ_PART)
#define SZ_V (B * O_CAPS * OD)                        // 32,768
#define OFF_OUTC (OFF_VBUF + SZ_V)
#define OFF_WT (OFF_OUTC + SZ_V)
#define SZ_WT (PCH * 9 * PCH)                         // 2,359,296
#define OFF_BIAS (OFF_WT + SZ_WT)
#define OFF_H OFF_BLOG  // reuse blog region for h (blog dead by then)

// ---------------------------------------------------------------------------
// K0: transpose conv weights to [ci*9+tap][co] (co fast) with BN scale folded;
// also compute folded bias.
// ---------------------------------------------------------------------------
__global__ __launch_bounds__(256) void prep_w(
    const float* __restrict__ cw, const float* __restrict__ gamma,
    const float* __restrict__ beta, const float* __restrict__ mean,
    const float* __restrict__ var, float* __restrict__ wt,
    float* __restrict__ bias) {
  const int co = blockIdx.x;  // 512 blocks
  const float inv = gamma[co] * rsqrtf(var[co] + 1e-5f);
  if (threadIdx.x == 0) bias[co] = beta[co] - mean[co] * inv;
  for (int idx = threadIdx.x; idx < PCH * 9; idx += 256)
    wt[(size_t)idx * PCH + co] = cw[(size_t)co * (PCH * 9) + idx] * inv;
}

// ---------------------------------------------------------------------------
// K1: conv3x3 SAME + folded BN + ReLU + squash(k=8) -> pose[b,i,k]
// block: (b, co-tile of 64). 256 threads = 64 px * 4 co-groups of 16.
// lw reads are wave-broadcast (cg uniform per wave) -> conflict-free.
// ---------------------------------------------------------------------------
__global__ __launch_bounds__(256) void conv_bn_squash(
    const float* __restrict__ x, const float* __restrict__ wt,
    const float* __restrict__ bias, float* __restrict__ pose) {
  __shared__ float lx[16 * 100];       // 6.25 KB, 10x10 padded per ci
  __shared__ float lw[16 * 9 * 64];    // 36 KB: [ci*9+tap][co]
  __shared__ float lbias[64];
  const int b = blockIdx.x;
  const int co0 = blockIdx.y * 64;
  const int tid = threadIdx.x;
  if (tid < 64) lbias[tid] = bias[co0 + tid];
  for (int t = tid; t < 1600; t += 256) lx[t] = 0.f;

  const int p = tid & 63, cg = tid >> 6;
  const int h = p >> 3, w = p & 7;
  float acc[16];
#pragma unroll
  for (int c = 0; c < 16; ++c) acc[c] = 0.f;

  for (int ci0 = 0; ci0 < PCH; ci0 += 16) {
    __syncthreads();
    for (int idx = tid; idx < 1024; idx += 256) {
      const int ci = idx >> 6, px = idx & 63;
      lx[ci * 100 + 11 + (px >> 3) * 10 + (px & 7)] =
          x[((size_t)b * PCH + ci0 + ci) * 64 + px];
    }
    for (int idx = tid; idx < 9216; idx += 256) {
      const int r = idx >> 6, c = idx & 63;  // r = ci*9+tap
      lw[idx] = wt[(size_t)(ci0 * 9 + r) * PCH + co0 + c];
    }
    __syncthreads();
    for (int ci = 0; ci < 16; ++ci) {
      const float* lxp = lx + ci * 100 + h * 10 + w;
      float xv[9];
      xv[0] = lxp[0];  xv[1] = lxp[1];  xv[2] = lxp[2];
      xv[3] = lxp[10]; xv[4] = lxp[11]; xv[5] = lxp[12];
      xv[6] = lxp[20]; xv[7] = lxp[21]; xv[8] = lxp[22];
#pragma unroll
      for (int t = 0; t < 9; ++t) {
        const float4* wq = (const float4*)&lw[(ci * 9 + t) * 64 + cg * 16];
#pragma unroll
        for (int q = 0; q < 4; ++q) {
          const float4 wv = wq[q];
          acc[q * 4 + 0] += wv.x * xv[t];
          acc[q * 4 + 1] += wv.y * xv[t];
          acc[q * 4 + 2] += wv.z * xv[t];
          acc[q * 4 + 3] += wv.w * xv[t];
        }
      }
    }
  }
#pragma unroll
  for (int c = 0; c < 16; ++c) acc[c] = fmaxf(acc[c] + lbias[cg * 16 + c], 0.f);
#pragma unroll
  for (int g = 0; g < 2; ++g) {
    float ms = 0.f;
#pragma unroll
    for (int j = 0; j < 8; ++j) ms += acc[g * 8 + j] * acc[g * 8 + j];
    const float sc = ms / (1.f + ms) / (sqrtf(ms) + 1e-8f);
    const int cap = (co0 >> 3) + cg * 2 + g;
    float* dst = pose + ((size_t)b * I_CAPS + cap * 64 + p) * IDC;
#pragma unroll
    for (int j = 0; j < 8; ++j) dst[j] = acc[g * 8 + j] * sc;
  }
}

// ---------------------------------------------------------------------------
// Routing phase v3: block = 16 i's x 32 b's, 8 waves. Wave owns 4 b's and
// loops all i -> c*X partial accumulates in REGISTERS acc[4][8] (no LDS
// accumulator, no atomics). W staged once per block into LDS (double-
// buffered, pitch-65 float4 swizzle => conflict-free writes AND b128 reads).
// lane = o*2+dh. Partials layout [bl][o][d] -> coalesced float4 stores.
// ---------------------------------------------------------------------------
template <int MODE>
__global__ __launch_bounds__(512, 2) void routing_phase(
    const float* __restrict__ pose, const float* __restrict__ capsw,
    const float* __restrict__ vbuf, float* __restrict__ blog,
    float* __restrict__ partials) {
  __shared__ float4 lw4[2][16 * 65];  // 2 x 16.6 KB
  const int tid = threadIdx.x;
  const int lane = tid & 63;
  const int wv = tid >> 6;
  const int o = lane >> 1, dh = lane & 1;
  const int i0 = blockIdx.x * ICHUNK;
  const int b0 = blockIdx.y * 32;

  const float4* cw4 = (const float4*)capsw;
  // staging: thread t loads 2 float4s for lane-slot sl, chunks sq and sq+8
  const int sl = tid >> 3;  // 0..63
  const int sq = tid & 7;   // 0..7
  const size_t gbase =
      (size_t)(sl >> 1) * (I_CAPS * 32) + (size_t)(sl & 1) * 16 + sq;

  float acc[4][8];
#pragma unroll
  for (int bb = 0; bb < 4; ++bb)
#pragma unroll
    for (int j = 0; j < 8; ++j) acc[bb][j] = 0.f;

  // prologue stage i0 -> buf 0
  {
    const size_t g = gbase + (size_t)i0 * 32;
    lw4[0][sq * 65 + sl] = cw4[g];
    lw4[0][(sq + 8) * 65 + sl] = cw4[g + 8];
  }
  __syncthreads();

  for (int ii = 0; ii < ICHUNK; ++ii) {
    const int buf = ii & 1;
    if (ii + 1 < ICHUNK) {
      const size_t g = gbase + (size_t)(i0 + ii + 1) * 32;
      lw4[buf ^ 1][sq * 65 + sl] = cw4[g];
      lw4[buf ^ 1][(sq + 8) * 65 + sl] = cw4[g + 8];
    }
    const int i = i0 + ii;
    float wf[64];
#pragma unroll
    for (int q = 0; q < 16; ++q) {
      const float4 v4 = lw4[buf][q * 65 + lane];
      wf[q * 4 + 0] = v4.x; wf[q * 4 + 1] = v4.y;
      wf[q * 4 + 2] = v4.z; wf[q * 4 + 3] = v4.w;
    }
#pragma unroll
    for (int bb = 0; bb < 4; ++bb) {
      const int b = b0 + wv * 4 + bb;
      const float4* pp = (const float4*)(pose + ((size_t)b * I_CAPS + i) * IDC);
      const float4 p0 = pp[0], p1 = pp[1];
      const float pk[8] = {p0.x, p0.y, p0.z, p0.w, p1.x, p1.y, p1.z, p1.w};
      float X[8];
#pragma unroll
      for (int j = 0; j < 8; ++j) {
        float s = 0.f;
#pragma unroll
        for (int k = 0; k < 8; ++k) s += wf[j * 8 + k] * pk[k];
        X[j] = s;
      }
      float c;
      if (MODE == 0) {
        c = 1.0f / 32.0f;
      } else {
        const float* vrow = vbuf + ((size_t)(b * O_CAPS + o) * OD) + dh * 8;
        float lg = 0.f;
#pragma unroll
        for (int j = 0; j < 8; ++j) lg += vrow[j] * X[j];
        lg += __shfl_xor(lg, 1, 64);  // full v.X over 16 d on both dh-halves
        const size_t bidx = ((size_t)b * I_CAPS + i) * O_CAPS + o;
        if (MODE == 2) lg += blog[bidx];
        if (MODE == 1 && dh == 0) blog[bidx] = lg;
        float mx = lg;
#pragma unroll
        for (int s = 2; s < 64; s <<= 1) mx = fmaxf(mx, __shfl_xor(mx, s, 64));
        const float e = __expf(lg - mx);
        float sm = e;
#pragma unroll
        for (int s = 2; s < 64; s <<= 1) sm += __shfl_xor(sm, s, 64);
        c = e / sm;
      }
#pragma unroll
      for (int j = 0; j < 8; ++j) acc[bb][j] += c * X[j];
    }
    __syncthreads();
  }

  // write partials: [bl][o*16 + dh*8 + j], coalesced per wave
  const size_t pbase = ((size_t)blockIdx.x * 2 + blockIdx.y) * (32 * 512);
#pragma unroll
  for (int bb = 0; bb < 4; ++bb) {
    const int bl = wv * 4 + bb;
    float4* dst =
        (float4*)(partials + pbase + (size_t)bl * 512 + o * 16 + dh * 8);
    dst[0] = make_float4(acc[bb][0], acc[bb][1], acc[bb][2], acc[bb][3]);
    dst[1] = make_float4(acc[bb][4], acc[bb][5], acc[bb][6], acc[bb][7]);
  }
}

// ---------------------------------------------------------------------------
// Reduce partials over the 256 i-chunks, then squash over d -> dst[b][o][d]
// partials elem layout: [chunk*2+bh][bl][o*16+d]
// ---------------------------------------------------------------------------
__global__ __launch_bounds__(256) void reduce_squash(
    const float* __restrict__ partials, float* __restrict__ dst) {
  const int t = blockIdx.x * 256 + threadIdx.x;  // 0..32767 -> (b,o,d)
  const int b = t >> 9;
  const int r = t & 511;  // o*16+d
  const int bh = b >> 5, bl = b & 31;
  const size_t elem = (size_t)bl * 512 + r;
  float s = 0.f;
  for (int blk = 0; blk < NPBLK; ++blk)
    s += partials[(size_t)(blk * 2 + bh) * (32 * 512) + elem];
  float sq = s * s;
  sq += __shfl_xor(sq, 1, 64);
  sq += __shfl_xor(sq, 2, 64);
  sq += __shfl_xor(sq, 4, 64);
  sq += __shfl_xor(sq, 8, 64);
  const float sc = sq / (1.f + sq) / (sqrtf(sq) + 1e-8f);
  dst[t] = s * sc;
}

// ---------------------------------------------------------------------------
// VAE head
// ---------------------------------------------------------------------------
__global__ __launch_bounds__(256) void fc1_relu(
    const float* __restrict__ outc, const float* __restrict__ w1,
    const float* __restrict__ b1, float* __restrict__ h) {
  const int gid = blockIdx.x * 256 + threadIdx.x;  // < 2048*1024
  const int n = gid >> 10, j = gid & 1023;
  float s = b1[j];
#pragma unroll
  for (int k = 0; k < 16; ++k) s += outc[n * 16 + k] * w1[k * 1024 + j];
  h[gid] = fmaxf(s, 0.f);
}

__global__ __launch_bounds__(256) void fc2_mu(
    const float* __restrict__ h, const float* __restrict__ w2,
    const float* __restrict__ b2, float* __restrict__ dout) {
  __shared__ float lh[4 * 1024];
  const int tid = threadIdx.x;
  const int nl = tid >> 6, m = tid & 63;
  const int n0 = blockIdx.x * 4;
  for (int idx = tid; idx < 4096; idx += 256)
    lh[idx] = h[(size_t)n0 * 1024 + idx];
  __syncthreads();
  float s = b2[m];
  const float* hr = lh + nl * 1024;
#pragma unroll 8
  for (int j = 0; j < 1024; ++j) s += hr[j] * w2[j * 64 + m];
  const int n = n0 + nl;
  dout[n * 64 + m] = s;            // z
  dout[131072 + n * 64 + m] = s;   // z_mu
}

__global__ __launch_bounds__(256) void fc_var(
    const float* __restrict__ outc, const float* __restrict__ wv,
    const float* __restrict__ bv, float* __restrict__ dout) {
  const int gid = blockIdx.x * 256 + threadIdx.x;  // < 131072
  const int n = gid >> 6, m = gid & 63;
  float s = bv[m];
#pragma unroll
  for (int k = 0; k < 16; ++k) s += outc[n * 16 + k] * wv[k * 64 + m];
  const float sp = (s > 0.f) ? (s + log1pf(__expf(-s))) : log1pf(__expf(s));
  dout[262144 + gid] = sp + 1e-8f;
}

// ---------------------------------------------------------------------------
extern "C" void kernel_launch(void* const* d_in, const int* in_sizes, int n_in,
                              void* d_out, int out_size, void* d_ws,
                              size_t ws_size, hipStream_t stream) {
  const float* x = (const float*)d_in[0];
  const float* conv_w = (const float*)d_in[1];
  const float* bn_gamma = (const float*)d_in[2];
  const float* bn_beta = (const float*)d_in[3];
  const float* bn_mean = (const float*)d_in[4];
  const float* bn_var = (const float*)d_in[5];
  const float* caps_w = (const float*)d_in[6];
  const float* fcm_w1 = (const float*)d_in[7];
  const float* fcm_b1 = (const float*)d_in[8];
  const float* fcm_w2 = (const float*)d_in[9];
  const float* fcm_b2 = (const float*)d_in[10];
  const float* fcv_w = (const float*)d_in[11];
  const float* fcv_b = (const float*)d_in[12];
  float* out = (float*)d_out;
  float* ws = (float*)d_ws;

  float* pose = ws + OFF_POSE;
  float* blog = ws + OFF_BLOG;
  float* part = ws + OFF_PART;
  float* vbuf = ws + OFF_VBUF;
  float* outc = ws + OFF_OUTC;
  float* wt = ws + OFF_WT;
  float* bias = ws + OFF_BIAS;
  float* h = ws + OFF_H;

  prep_w<<<512, 256, 0, stream>>>(conv_w, bn_gamma, bn_beta, bn_mean, bn_var,
                                  wt, bias);
  conv_bn_squash<<<dim3(64, 8), 256, 0, stream>>>(x, wt, bias, pose);

  routing_phase<0><<<dim3(NPBLK, 2), 512, 0, stream>>>(
      pose, caps_w, nullptr, nullptr, part);
  reduce_squash<<<128, 256, 0, stream>>>(part, vbuf);

  routing_phase<1><<<dim3(NPBLK, 2), 512, 0, stream>>>(
      pose, caps_w, vbuf, blog, part);
  reduce_squash<<<128, 256, 0, stream>>>(part, vbuf);

  routing_phase<2><<<dim3(NPBLK, 2), 512, 0, stream>>>(
      pose, caps_w, vbuf, blog, part);
  reduce_squash<<<128, 256, 0, stream>>>(part, outc);

  fc1_relu<<<8192, 256, 0, stream>>>(outc, fcm_w1, fcm_b1, h);
  fc2_mu<<<512, 256, 0, stream>>>(h, fcm_w2, fcm_b2, out);
  fc_var<<<512, 256, 0, stream>>>(outc, fcv_w, fcv_b, out);
}

// Round 4
// 603.902 us; speedup vs baseline: 4.7216x; 1.6091x over previous
//
#include <hip/hip_runtime.h>
#include <cstdint>
#include <cstddef>

#define B 64
#define PCH 512
#define O_CAPS 32
#define OD 16
#define IDC 8
#define I_CAPS 4096
#define ICHUNK 16
#define NPBLK 256  // I_CAPS / ICHUNK
#define KDIM 4608  // 512*9

typedef __attribute__((ext_vector_type(8))) short bf16x8;
typedef __attribute__((ext_vector_type(4))) float f32x4;

// workspace layout (in floats)
#define OFF_POSE 0
#define SZ_POSE (B * I_CAPS * IDC)                    // 2,097,152
#define OFF_BLOG (OFF_POSE + SZ_POSE)
#define SZ_BLOG ((size_t)B * I_CAPS * O_CAPS)         // 8,388,608
#define OFF_PART (OFF_BLOG + SZ_BLOG)
#define SZ_PART ((size_t)NPBLK * 2 * 32 * 512)        // 8,388,608
#define OFF_VBUF (OFF_PART + SZ_PART)
#define SZ_V (B * O_CAPS * OD)                        // 32,768
#define OFF_OUTC (OFF_VBUF + SZ_V)
#define OFF_WB (OFF_OUTC + SZ_V)                      // bf16 512*4608 = 1,179,648 floats
#define OFF_BIAS (OFF_WB + (PCH * KDIM) / 2)
// Aim (bf16 4096*4608 = 9,437,184 float-equiv) aliases blog+part head: dead
// before routing<0> writes part / routing<1> writes blog.
#define OFF_AIM OFF_BLOG
#define OFF_H OFF_BLOG  // h (2M floats) reuses blog after routing

__device__ inline unsigned short f2bf(float f) {
  union { float f; unsigned int u; } v; v.f = f;
  unsigned int r = v.u + 0x7fff + ((v.u >> 16) & 1);  // RNE
  return (unsigned short)(r >> 16);
}

// ---------------------------------------------------------------------------
// prep_wb: Wb[n][k] = bf16(conv_w[n][k] * inv[n]); bias[n] = beta - mean*inv.
// ---------------------------------------------------------------------------
__global__ __launch_bounds__(256) void prep_wb(
    const float* __restrict__ cw, const float* __restrict__ gamma,
    const float* __restrict__ beta, const float* __restrict__ mean,
    const float* __restrict__ var, unsigned short* __restrict__ wb,
    float* __restrict__ bias) {
  const int n = blockIdx.x;
  const float inv = gamma[n] * rsqrtf(var[n] + 1e-5f);
  if (threadIdx.x == 0) bias[n] = beta[n] - mean[n] * inv;
  for (int k = threadIdx.x; k < KDIM; k += 256)
    wb[(size_t)n * KDIM + k] = f2bf(cw[(size_t)n * KDIM + k] * inv);
}

// ---------------------------------------------------------------------------
// prep_aim: im2col to bf16. Aim[m=(b,px)][k=ci*9+tap] = xpad[b,ci,h+kh-1,w+kw-1]
// block = (b, ci-chunk of 32). LDS stage padded 10x10 tiles; ushort4 writes.
// ---------------------------------------------------------------------------
__global__ __launch_bounds__(256) void prep_aim(
    const float* __restrict__ x, unsigned short* __restrict__ aim) {
  __shared__ float lxp[32 * 100];  // 12.8 KB padded 10x10 per ci
  const int b = blockIdx.x;
  const int ci0 = blockIdx.y * 32;
  const int tid = threadIdx.x;
  for (int t = tid; t < 3200; t += 256) lxp[t] = 0.f;
  __syncthreads();
  for (int t = tid; t < 2048; t += 256) {
    const int ci = t >> 6, px = t & 63;
    lxp[ci * 100 + 11 + (px >> 3) * 10 + (px & 7)] =
        x[((size_t)b * PCH + ci0 + ci) * 64 + px];
  }
  __syncthreads();
  // 64 px * 72 quads of 4 k's each
  for (int t = tid; t < 4608; t += 256) {
    const int px = t / 72;
    const int kk = (t - px * 72) * 4;
    unsigned short v[4];
#pragma unroll
    for (int j = 0; j < 4; ++j) {
      const int k = kk + j;
      const int ci = k / 9;
      const int tap = k - ci * 9;
      const int kh = tap / 3, kw = tap - kh * 3;
      v[j] = f2bf(lxp[ci * 100 + ((px >> 3) + kh) * 10 + (px & 7) + kw]);
    }
    ushort4* dst =
        (ushort4*)(aim + (size_t)(b * 64 + px) * KDIM + ci0 * 9 + kk);
    *dst = make_ushort4(v[0], v[1], v[2], v[3]);
  }
}

// ---------------------------------------------------------------------------
// conv_gemm: C[4096 m][512 n] = Aim x Wb^T (both [row][k] bf16, k-fast).
// Tile 64m x 64n, 4 waves of 32x32 (2x2 grid). BK=64, mfma 16x16x32_bf16.
// global_load_lds width-16 staging with XOR seg swizzle (conflict-free b128
// reads despite wave-uniform-base constraint). Epilogue: bias+ReLU+squash
// (capsule dim = n&7 = lane&7, shfl_xor 1/2/4) -> pose.
// ---------------------------------------------------------------------------
__global__ __launch_bounds__(256) void conv_gemm(
    const unsigned short* __restrict__ aim, const unsigned short* __restrict__ wb,
    const float* __restrict__ bias, float* __restrict__ pose) {
  __shared__ unsigned short lA[64 * 64];  // 8 KB  [row][seg^(row&7)]
  __shared__ unsigned short lB[64 * 64];  // 8 KB
  const int tid = threadIdx.x;
  const int lane = tid & 63, wv = tid >> 6;
  const int wm = wv & 1, wn = wv >> 1;  // wave grid 2x2
  const int n0 = blockIdx.x * 64;
  const int m0 = blockIdx.y * 64;  // = batch * 64
  const int rsub = lane >> 3, seg = lane & 7;

  f32x4 acc[2][2];
#pragma unroll
  for (int a = 0; a < 2; ++a)
#pragma unroll
    for (int c = 0; c < 2; ++c) acc[a][c] = (f32x4){0.f, 0.f, 0.f, 0.f};

  for (int k0 = 0; k0 < KDIM; k0 += 64) {
    __syncthreads();
#pragma unroll
    for (int it = 0; it < 2; ++it) {
      const int r = it * 32 + wv * 8 + rsub;
      const int c = seg ^ (r & 7);
      const unsigned short* ga =
          aim + (size_t)(m0 + r) * KDIM + k0 + c * 8;
      __builtin_amdgcn_global_load_lds(
          (const __attribute__((address_space(1))) void*)ga,
          (__attribute__((address_space(3))) void*)(lA + (it * 32 + wv * 8) * 64),
          16, 0, 0);
      const unsigned short* gb =
          wb + (size_t)(n0 + r) * KDIM + k0 + c * 8;
      __builtin_amdgcn_global_load_lds(
          (const __attribute__((address_space(1))) void*)gb,
          (__attribute__((address_space(3))) void*)(lB + (it * 32 + wv * 8) * 64),
          16, 0, 0);
    }
    __syncthreads();
#pragma unroll
    for (int kc = 0; kc < 2; ++kc) {
      const int g = kc * 4 + (lane >> 4);
      const int ml = wm * 32 + (lane & 15);
      const int nl = wn * 32 + (lane & 15);
      const int sa = (g ^ (ml & 7)) * 8;
      const int sb = (g ^ (nl & 7)) * 8;
      const bf16x8 a0 = *(const bf16x8*)(lA + (ml + 0) * 64 + sa);
      const bf16x8 a1 = *(const bf16x8*)(lA + (ml + 16) * 64 + sa);
      const bf16x8 b0 = *(const bf16x8*)(lB + (nl + 0) * 64 + sb);
      const bf16x8 b1 = *(const bf16x8*)(lB + (nl + 16) * 64 + sb);
      acc[0][0] = __builtin_amdgcn_mfma_f32_16x16x32_bf16(a0, b0, acc[0][0], 0, 0, 0);
      acc[0][1] = __builtin_amdgcn_mfma_f32_16x16x32_bf16(a0, b1, acc[0][1], 0, 0, 0);
      acc[1][0] = __builtin_amdgcn_mfma_f32_16x16x32_bf16(a1, b0, acc[1][0], 0, 0, 0);
      acc[1][1] = __builtin_amdgcn_mfma_f32_16x16x32_bf16(a1, b1, acc[1][1], 0, 0, 0);
    }
  }

  // epilogue: bias + relu + squash(8 consecutive n) -> pose[b][i][n&7]
  const int bq = blockIdx.y;
  float bsv[2];
#pragma unroll
  for (int ni = 0; ni < 2; ++ni)
    bsv[ni] = bias[n0 + wn * 32 + ni * 16 + (lane & 15)];
#pragma unroll
  for (int mi = 0; mi < 2; ++mi) {
#pragma unroll
    for (int ni = 0; ni < 2; ++ni) {
      const int n = n0 + wn * 32 + ni * 16 + (lane & 15);
#pragma unroll
      for (int reg = 0; reg < 4; ++reg) {
        float v = fmaxf(acc[mi][ni][reg] + bsv[ni], 0.f);
        float s2 = v * v;
        s2 += __shfl_xor(s2, 1, 64);
        s2 += __shfl_xor(s2, 2, 64);
        s2 += __shfl_xor(s2, 4, 64);
        const float sc = s2 / (1.f + s2) / (sqrtf(s2) + 1e-8f);
        const int px = wm * 32 + mi * 16 + (lane >> 4) * 4 + reg;
        pose[((size_t)bq * I_CAPS + (n >> 3) * 64 + px) * IDC + (n & 7)] =
            v * sc;
      }
    }
  }
}

// ---------------------------------------------------------------------------
// Routing phase v3 (unchanged from round 3): register accumulation,
// double-buffered LDS W staging, pitch-65 float4 swizzle.
// ---------------------------------------------------------------------------
template <int MODE>
__global__ __launch_bounds__(512, 2) void routing_phase(
    const float* __restrict__ pose, const float* __restrict__ capsw,
    const float* __restrict__ vbuf, float* __restrict__ blog,
    float* __restrict__ partials) {
  __shared__ float4 lw4[2][16 * 65];
  const int tid = threadIdx.x;
  const int lane = tid & 63;
  const int wv = tid >> 6;
  const int o = lane >> 1, dh = lane & 1;
  const int i0 = blockIdx.x * ICHUNK;
  const int b0 = blockIdx.y * 32;

  const float4* cw4 = (const float4*)capsw;
  const int sl = tid >> 3;
  const int sq = tid & 7;
  const size_t gbase =
      (size_t)(sl >> 1) * (I_CAPS * 32) + (size_t)(sl & 1) * 16 + sq;

  float acc[4][8];
#pragma unroll
  for (int bb = 0; bb < 4; ++bb)
#pragma unroll
    for (int j = 0; j < 8; ++j) acc[bb][j] = 0.f;

  {
    const size_t g = gbase + (size_t)i0 * 32;
    lw4[0][sq * 65 + sl] = cw4[g];
    lw4[0][(sq + 8) * 65 + sl] = cw4[g + 8];
  }
  __syncthreads();

  for (int ii = 0; ii < ICHUNK; ++ii) {
    const int buf = ii & 1;
    if (ii + 1 < ICHUNK) {
      const size_t g = gbase + (size_t)(i0 + ii + 1) * 32;
      lw4[buf ^ 1][sq * 65 + sl] = cw4[g];
      lw4[buf ^ 1][(sq + 8) * 65 + sl] = cw4[g + 8];
    }
    const int i = i0 + ii;
    float wf[64];
#pragma unroll
    for (int q = 0; q < 16; ++q) {
      const float4 v4 = lw4[buf][q * 65 + lane];
      wf[q * 4 + 0] = v4.x; wf[q * 4 + 1] = v4.y;
      wf[q * 4 + 2] = v4.z; wf[q * 4 + 3] = v4.w;
    }
#pragma unroll
    for (int bb = 0; bb < 4; ++bb) {
      const int b = b0 + wv * 4 + bb;
      const float4* pp = (const float4*)(pose + ((size_t)b * I_CAPS + i) * IDC);
      const float4 p0 = pp[0], p1 = pp[1];
      const float pk[8] = {p0.x, p0.y, p0.z, p0.w, p1.x, p1.y, p1.z, p1.w};
      float X[8];
#pragma unroll
      for (int j = 0; j < 8; ++j) {
        float s = 0.f;
#pragma unroll
        for (int k = 0; k < 8; ++k) s += wf[j * 8 + k] * pk[k];
        X[j] = s;
      }
      float c;
      if (MODE == 0) {
        c = 1.0f / 32.0f;
      } else {
        const float* vrow = vbuf + ((size_t)(b * O_CAPS + o) * OD) + dh * 8;
        float lg = 0.f;
#pragma unroll
        for (int j = 0; j < 8; ++j) lg += vrow[j] * X[j];
        lg += __shfl_xor(lg, 1, 64);
        const size_t bidx = ((size_t)b * I_CAPS + i) * O_CAPS + o;
        if (MODE == 2) lg += blog[bidx];
        if (MODE == 1 && dh == 0) blog[bidx] = lg;
        float mx = lg;
#pragma unroll
        for (int s = 2; s < 64; s <<= 1) mx = fmaxf(mx, __shfl_xor(mx, s, 64));
        const float e = __expf(lg - mx);
        float sm = e;
#pragma unroll
        for (int s = 2; s < 64; s <<= 1) sm += __shfl_xor(sm, s, 64);
        c = e / sm;
      }
#pragma unroll
      for (int j = 0; j < 8; ++j) acc[bb][j] += c * X[j];
    }
    __syncthreads();
  }

  const size_t pbase = ((size_t)blockIdx.x * 2 + blockIdx.y) * (32 * 512);
#pragma unroll
  for (int bb = 0; bb < 4; ++bb) {
    const int bl = wv * 4 + bb;
    float4* dst =
        (float4*)(partials + pbase + (size_t)bl * 512 + o * 16 + dh * 8);
    dst[0] = make_float4(acc[bb][0], acc[bb][1], acc[bb][2], acc[bb][3]);
    dst[1] = make_float4(acc[bb][4], acc[bb][5], acc[bb][6], acc[bb][7]);
  }
}

// ---------------------------------------------------------------------------
__global__ __launch_bounds__(256) void reduce_squash(
    const float* __restrict__ partials, float* __restrict__ dst) {
  const int t = blockIdx.x * 256 + threadIdx.x;  // (b,o,d)
  const int b = t >> 9;
  const int r = t & 511;  // o*16+d
  const int bh = b >> 5, bl = b & 31;
  const size_t elem = (size_t)bl * 512 + r;
  float s = 0.f;
  for (int blk = 0; blk < NPBLK; ++blk)
    s += partials[(size_t)(blk * 2 + bh) * (32 * 512) + elem];
  float sq = s * s;
  sq += __shfl_xor(sq, 1, 64);
  sq += __shfl_xor(sq, 2, 64);
  sq += __shfl_xor(sq, 4, 64);
  sq += __shfl_xor(sq, 8, 64);
  const float sc = sq / (1.f + sq) / (sqrtf(sq) + 1e-8f);
  dst[t] = s * sc;
}

// ---------------------------------------------------------------------------
// VAE head
// ---------------------------------------------------------------------------
__global__ __launch_bounds__(256) void fc1_relu(
    const float* __restrict__ outc, const float* __restrict__ w1,
    const float* __restrict__ b1, float* __restrict__ h) {
  const int gid = blockIdx.x * 256 + threadIdx.x;
  const int n = gid >> 10, j = gid & 1023;
  float s = b1[j];
#pragma unroll
  for (int k = 0; k < 16; ++k) s += outc[n * 16 + k] * w1[k * 1024 + j];
  h[gid] = fmaxf(s, 0.f);
}

__global__ __launch_bounds__(256) void fc2_mu(
    const float* __restrict__ h, const float* __restrict__ w2,
    const float* __restrict__ b2, float* __restrict__ dout) {
  __shared__ float lh[4 * 1024];
  const int tid = threadIdx.x;
  const int nl = tid >> 6, m = tid & 63;
  const int n0 = blockIdx.x * 4;
  for (int idx = tid; idx < 4096; idx += 256)
    lh[idx] = h[(size_t)n0 * 1024 + idx];
  __syncthreads();
  float s = b2[m];
  const float* hr = lh + nl * 1024;
#pragma unroll 8
  for (int j = 0; j < 1024; ++j) s += hr[j] * w2[j * 64 + m];
  const int n = n0 + nl;
  dout[n * 64 + m] = s;
  dout[131072 + n * 64 + m] = s;
}

__global__ __launch_bounds__(256) void fc_var(
    const float* __restrict__ outc, const float* __restrict__ wv,
    const float* __restrict__ bv, float* __restrict__ dout) {
  const int gid = blockIdx.x * 256 + threadIdx.x;
  const int n = gid >> 6, m = gid & 63;
  float s = bv[m];
#pragma unroll
  for (int k = 0; k < 16; ++k) s += outc[n * 16 + k] * wv[k * 64 + m];
  const float sp = (s > 0.f) ? (s + log1pf(__expf(-s))) : log1pf(__expf(s));
  dout[262144 + gid] = sp + 1e-8f;
}

// ---------------------------------------------------------------------------
extern "C" void kernel_launch(void* const* d_in, const int* in_sizes, int n_in,
                              void* d_out, int out_size, void* d_ws,
                              size_t ws_size, hipStream_t stream) {
  const float* x = (const float*)d_in[0];
  const float* conv_w = (const float*)d_in[1];
  const float* bn_gamma = (const float*)d_in[2];
  const float* bn_beta = (const float*)d_in[3];
  const float* bn_mean = (const float*)d_in[4];
  const float* bn_var = (const float*)d_in[5];
  const float* caps_w = (const float*)d_in[6];
  const float* fcm_w1 = (const float*)d_in[7];
  const float* fcm_b1 = (const float*)d_in[8];
  const float* fcm_w2 = (const float*)d_in[9];
  const float* fcm_b2 = (const float*)d_in[10];
  const float* fcv_w = (const float*)d_in[11];
  const float* fcv_b = (const float*)d_in[12];
  float* out = (float*)d_out;
  float* ws = (float*)d_ws;

  float* pose = ws + OFF_POSE;
  float* blog = ws + OFF_BLOG;
  float* part = ws + OFF_PART;
  float* vbuf = ws + OFF_VBUF;
  float* outc = ws + OFF_OUTC;
  unsigned short* wbq = (unsigned short*)(ws + OFF_WB);
  float* bias = ws + OFF_BIAS;
  unsigned short* aim = (unsigned short*)(ws + OFF_AIM);
  float* h = ws + OFF_H;

  prep_wb<<<512, 256, 0, stream>>>(conv_w, bn_gamma, bn_beta, bn_mean, bn_var,
                                   wbq, bias);
  prep_aim<<<dim3(64, 16), 256, 0, stream>>>(x, aim);
  conv_gemm<<<dim3(8, 64), 256, 0, stream>>>(aim, wbq, bias, pose);

  routing_phase<0><<<dim3(NPBLK, 2), 512, 0, stream>>>(
      pose, caps_w, nullptr, nullptr, part);
  reduce_squash<<<128, 256, 0, stream>>>(part, vbuf);

  routing_phase<1><<<dim3(NPBLK, 2), 512, 0, stream>>>(
      pose, caps_w, vbuf, blog, part);
  reduce_squash<<<128, 256, 0, stream>>>(part, vbuf);

  routing_phase<2><<<dim3(NPBLK, 2), 512, 0, stream>>>(
      pose, caps_w, vbuf, blog, part);
  reduce_squash<<<128, 256, 0, stream>>>(part, outc);

  fc1_relu<<<8192, 256, 0, stream>>>(outc, fcm_w1, fcm_b1, h);
  fc2_mu<<<512, 256, 0, stream>>>(h, fcm_w2, fcm_b2, out);
  fc_var<<<512, 256, 0, stream>>>(outc, fcv_w, fcv_b, out);
}